// Round 1
// baseline (4933.950 us; speedup 1.0000x reference)
//
#include <hip/hip_runtime.h>
#include <hip/hip_bf16.h>
#include <cstddef>

// Problem constants
#define BB 32
#define CC 320
#define HH 64
#define WW 64
#define CTX_DIM 1024
#define CTX_HW 16
#define K1 1026          // CTX_DIM + 2
#define NPIX 256         // 16*16
#define COT 20           // output channels per conv block (320/20 = 16 groups)
#define PLSTRIDE 48      // LDS plane row stride (mod 32 == 16 -> 2-way-only conflicts)

// ---------------------------------------------------------------------------
// Kernel 1: transpose context (B,256,1024) -> planar ctxT (B,1026,256)
// grid (B, 4 pixel-chunks, 16 ci-chunks), block 256
__global__ __launch_bounds__(256) void transpose_ctx(
    const float* __restrict__ ctx, float* __restrict__ ctxT) {
  int b = blockIdx.x, pc = blockIdx.y, cc = blockIdx.z;
  __shared__ float tile[64][65];
  int t = threadIdx.x;
  int r = t >> 6;       // 0..3
  int col = t & 63;
#pragma unroll
  for (int i = 0; i < 16; ++i) {
    int p = pc * 64 + i * 4 + r;
    tile[i * 4 + r][col] = ctx[((size_t)b * 256 + p) * 1024 + (size_t)cc * 64 + col];
  }
  __syncthreads();
#pragma unroll
  for (int i = 0; i < 16; ++i) {
    int ci = i * 4 + r;
    ctxT[((size_t)b * K1 + cc * 64 + ci) * NPIX + pc * 64 + col] = tile[col][ci];
  }
}

// ---------------------------------------------------------------------------
// Kernel 2: indicator channels 1024,1025 of ctxT
// grid B, block 256
__global__ __launch_bounds__(256) void fill_ind(
    const float* __restrict__ ind, float* __restrict__ ctxT) {
  int b = blockIdx.x;
  int t = threadIdx.x;
  float i0 = ind[b * 2 + 0];
  float i1 = ind[b * 2 + 1];
  ctxT[((size_t)b * K1 + 1024) * NPIX + t] = i0;
  ctxT[((size_t)b * K1 + 1025) * NPIX + t] = i1;
}

// ---------------------------------------------------------------------------
// Kernel 3: per-batch src maps.  sy[b][y] = source row (0..15) or -1 if masked.
// grid B, block 64
__global__ __launch_bounds__(64) void prep_maps(
    const float* __restrict__ bbox, int* __restrict__ sy, int* __restrict__ sx) {
  int b = blockIdx.x;
  int t = threadIdx.x;  // coordinate 0..63
  int x1 = (int)(bbox[b * 4 + 0] * (float)HH);
  int y1 = (int)(bbox[b * 4 + 1] * (float)HH);
  int x2 = max((int)(bbox[b * 4 + 2] * (float)HH), x1 + 1);
  int y2 = max((int)(bbox[b * 4 + 3] * (float)HH), y1 + 1);
  bool ok = (y2 <= HH) && (x2 <= WW) && (y1 >= 0) && (x1 >= 0);
  int vy = -1, vx = -1;
  if (ok && t >= y1 && t < y2) vy = min(15, max(0, ((t - y1) * CTX_HW) / (y2 - y1)));
  if (ok && t >= x1 && t < x2) vx = min(15, max(0, ((t - x1) * CTX_HW) / (x2 - x1)));
  sy[b * 64 + t] = vy;
  sx[b * 64 + t] = vx;
}

// ---------------------------------------------------------------------------
// Kernel 4/5: direct 3x3 SAME conv on 16x16 planes, planar layout.
// src: [B][K][256], w: [320][K][3][3], dst: [B][320][256]
// grid (B, 16 co-groups), block 256 (one thread per pixel), COT=20 co per block.
__global__ __launch_bounds__(256) void conv3x3(
    const float* __restrict__ src, const float* __restrict__ w,
    const float* __restrict__ bias, float* __restrict__ dst,
    int K, int apply_silu) {
  int b = blockIdx.x;
  int co0 = blockIdx.y * COT;
  int t = threadIdx.x;
  int y = t >> 4, x = t & 15;

  __shared__ float plane[18 * PLSTRIDE];
  for (int i = t; i < 18 * PLSTRIDE; i += 256) plane[i] = 0.0f;
  __syncthreads();

  float acc[COT];
#pragma unroll
  for (int j = 0; j < COT; ++j) acc[j] = 0.0f;

  const float* srcb = src + (size_t)b * K * NPIX;
  int center = (y + 1) * PLSTRIDE + (x + 1);

  for (int ci = 0; ci < K; ++ci) {
    float v = srcb[(size_t)ci * NPIX + t];
    __syncthreads();
    plane[center] = v;
    __syncthreads();
    float p00 = plane[y * PLSTRIDE + x];
    float p01 = plane[y * PLSTRIDE + x + 1];
    float p02 = plane[y * PLSTRIDE + x + 2];
    float p10 = plane[(y + 1) * PLSTRIDE + x];
    float p11 = plane[(y + 1) * PLSTRIDE + x + 1];
    float p12 = plane[(y + 1) * PLSTRIDE + x + 2];
    float p20 = plane[(y + 2) * PLSTRIDE + x];
    float p21 = plane[(y + 2) * PLSTRIDE + x + 1];
    float p22 = plane[(y + 2) * PLSTRIDE + x + 2];
    const float* wp = w + ((size_t)co0 * K + ci) * 9;
#pragma unroll
    for (int j = 0; j < COT; ++j) {
      const float* wj = wp + (size_t)j * K * 9;
      acc[j] += wj[0] * p00 + wj[1] * p01 + wj[2] * p02
              + wj[3] * p10 + wj[4] * p11 + wj[5] * p12
              + wj[6] * p20 + wj[7] * p21 + wj[8] * p22;
    }
  }

#pragma unroll
  for (int j = 0; j < COT; ++j) {
    float v = acc[j] + bias[co0 + j];
    if (apply_silu) v = v * (1.0f / (1.0f + __expf(-v)));
    dst[((size_t)b * CC + co0 + j) * NPIX + t] = v;
  }
}

// ---------------------------------------------------------------------------
// Kernel 6: out = global_x + masked gather of cx2.
// grid B*C*4, block 256, float4 per thread (1024 elements per block).
__global__ __launch_bounds__(256) void scatter_add(
    const float* __restrict__ gx, const float* __restrict__ cx2,
    const int* __restrict__ sy, const int* __restrict__ sx,
    float* __restrict__ out) {
  int blk = blockIdx.x;
  int part = blk & 3;
  int bc = blk >> 2;            // b*320 + c
  int b = bc / CC;
  int t = threadIdx.x;
  int e = part * 1024 + t * 4;  // element within the 64x64 plane
  int y = e >> 6, x0 = e & 63;
  size_t idx = (size_t)bc * 4096 + e;
  float4 g = *(const float4*)(gx + idx);
  int vy = sy[b * 64 + y];
  if (vy >= 0) {
    const float* cxp = cx2 + (size_t)bc * NPIX + vy * 16;
    int v0 = sx[b * 64 + x0 + 0]; if (v0 >= 0) g.x += cxp[v0];
    int v1 = sx[b * 64 + x0 + 1]; if (v1 >= 0) g.y += cxp[v1];
    int v2 = sx[b * 64 + x0 + 2]; if (v2 >= 0) g.z += cxp[v2];
    int v3 = sx[b * 64 + x0 + 3]; if (v3 >= 0) g.w += cxp[v3];
  }
  *(float4*)(out + idx) = g;
}

// ---------------------------------------------------------------------------
extern "C" void kernel_launch(void* const* d_in, const int* in_sizes, int n_in,
                              void* d_out, int out_size, void* d_ws, size_t ws_size,
                              hipStream_t stream) {
  const float* gx    = (const float*)d_in[0];
  const float* ctx   = (const float*)d_in[1];
  const float* ind   = (const float*)d_in[2];
  const float* bbox  = (const float*)d_in[3];
  const float* w_in  = (const float*)d_in[4];
  const float* b_in  = (const float*)d_in[5];
  const float* w_out = (const float*)d_in[6];
  const float* b_out = (const float*)d_in[7];
  float* out = (float*)d_out;

  float* ws   = (float*)d_ws;
  float* ctxT = ws;                                   // 32*1026*256 floats
  float* cx1  = ctxT + (size_t)BB * K1 * NPIX;        // 32*320*256
  float* cx2  = cx1 + (size_t)BB * CC * NPIX;         // 32*320*256
  int*   sy   = (int*)(cx2 + (size_t)BB * CC * NPIX); // 32*64
  int*   sx   = sy + BB * 64;

  transpose_ctx<<<dim3(BB, 4, 16), 256, 0, stream>>>(ctx, ctxT);
  fill_ind<<<BB, 256, 0, stream>>>(ind, ctxT);
  prep_maps<<<BB, 64, 0, stream>>>(bbox, sy, sx);
  conv3x3<<<dim3(BB, CC / COT), 256, 0, stream>>>(ctxT, w_in, b_in, cx1, K1, 1);
  conv3x3<<<dim3(BB, CC / COT), 256, 0, stream>>>(cx1, w_out, b_out, cx2, CC, 0);
  scatter_add<<<BB * CC * 4, 256, 0, stream>>>(gx, cx2, sy, sx, out);
}

// Round 2
// 502.846 us; speedup vs baseline: 9.8121x; 9.8121x over previous
//
#include <hip/hip_runtime.h>
#include <cstddef>

#define BB 32
#define CC 320
#define HH 64
#define WW 64
#define CTX_HW 16
#define NPIX 256

typedef __attribute__((ext_vector_type(8))) short bf16x8;
typedef __attribute__((ext_vector_type(4))) float f32x4;

__device__ inline ushort f2bf(float x) {
  union { float f; unsigned u; } v; v.f = x;
  unsigned r = v.u + 0x7fff + ((v.u >> 16) & 1);  // RNE
  return (ushort)(r >> 16);
}

// ---------------------------------------------------------------------------
// Cast context (B,256,1024) fp32 -> pixel-major bf16 ctxP[B][257][1056]
// (channels 1024/1025 = indicator, 1026..1055 = 0, row 256 = zeros).
// Also zeroes row 256 of cx1P[B][257][320].
__global__ __launch_bounds__(256) void cast_ctx(
    const float* __restrict__ ctx, const float* __restrict__ ind,
    ushort* __restrict__ ctxP, ushort* __restrict__ cx1P) {
  int b = blockIdx.x, p = blockIdx.y, t = threadIdx.x;
  ushort* orow = ctxP + ((size_t)b * 257 + p) * 1056;
  if (p < 256) {
    const float* irow = ctx + ((size_t)b * 256 + p) * 1024;
    float4 v = ((const float4*)irow)[t];
    ushort4 o;
    o.x = f2bf(v.x); o.y = f2bf(v.y); o.z = f2bf(v.z); o.w = f2bf(v.w);
    ((ushort4*)orow)[t] = o;
    if (t < 32) {
      float val = (t == 0) ? ind[b * 2] : (t == 1) ? ind[b * 2 + 1] : 0.0f;
      orow[1024 + t] = f2bf(val);
    }
  } else {
    ushort4 z = make_ushort4(0, 0, 0, 0);
    for (int i = t; i < 264; i += 256) ((ushort4*)orow)[i] = z;
    if (t < 80) ((ushort4*)(cx1P + ((size_t)b * 257 + 256) * 320))[t] = z;
  }
}

// ---------------------------------------------------------------------------
// Weight transform: w[CO=320][KIN][9] fp32 -> wT[9][320][KP] bf16 (ci zero-pad)
template <int KIN, int KP>
__global__ __launch_bounds__(256) void wt_tr(
    const float* __restrict__ w, ushort* __restrict__ wT) {
  size_t idx = (size_t)blockIdx.x * 256 + threadIdx.x;
  constexpr size_t total = (size_t)9 * 320 * KP;
  if (idx >= total) return;
  int ci = (int)(idx % KP);
  size_t rem = idx / KP;
  int co = (int)(rem % 320);
  int t = (int)(rem / 320);
  float v = (ci < KIN) ? w[((size_t)co * KIN + ci) * 9 + t] : 0.0f;
  wT[idx] = f2bf(v);
}

// ---------------------------------------------------------------------------
// Per-batch gather maps: sy[b][y] = source row 0..15 or -1 if masked.
__global__ __launch_bounds__(64) void prep_maps(
    const float* __restrict__ bbox, int* __restrict__ sy, int* __restrict__ sx) {
  int b = blockIdx.x;
  int t = threadIdx.x;
  int x1 = (int)(bbox[b * 4 + 0] * (float)HH);
  int y1 = (int)(bbox[b * 4 + 1] * (float)HH);
  int x2 = max((int)(bbox[b * 4 + 2] * (float)HH), x1 + 1);
  int y2 = max((int)(bbox[b * 4 + 3] * (float)HH), y1 + 1);
  bool ok = (y2 <= HH) && (x2 <= WW) && (y1 >= 0) && (x1 >= 0);
  int vy = -1, vx = -1;
  if (ok && t >= y1 && t < y2) vy = min(15, max(0, ((t - y1) * CTX_HW) / (y2 - y1)));
  if (ok && t >= x1 && t < x2) vx = min(15, max(0, ((t - x1) * CTX_HW) / (x2 - x1)));
  sy[b * 64 + t] = vy;
  sx[b * 64 + t] = vx;
}

// ---------------------------------------------------------------------------
// Implicit-GEMM 3x3 SAME conv on 16x16 planes via bf16 MFMA.
// src: pixel-major bf16 [BB][257][KP] (row 256 = zeros)
// wT : bf16 [9][320][KP]
// out: PLANAR_OUT ? fp32 [BB][320][256] : bf16 [BB][257][320] (row 256 untouched)
// Block = (b, 32-co tile), 512 threads = 8 waves; wave = 64 px x 16 co.
template <int KP, int NCHUNK, int SILU, int PLANAR_OUT>
__global__ __launch_bounds__(512) void conv_mfma(
    const ushort* __restrict__ src, const ushort* __restrict__ wT,
    const float* __restrict__ bias, void* __restrict__ dstv) {
  constexpr int PL = 40;  // LDS row stride (elems): 80B -> 16B aligned, ~2-way banks
  __shared__ ushort plane[257 * PL];

  int b = blockIdx.x;
  int co0 = blockIdx.y * 32;
  int tid = threadIdx.x;
  int wid = tid >> 6;
  int lane = tid & 63;
  int m = lane & 15;
  int quad = lane >> 4;
  int mg = wid >> 1;  // 0..3 : M-group (16 image rows / 4 groups of 4)
  int ng = wid & 1;   // 0..1 : N-group (16 co each)
  int y0 = mg * 4;
  int co = co0 + ng * 16 + m;

  if (tid < PL) plane[256 * PL + tid] = 0;  // permanent zero row

  f32x4 acc[4];
#pragma unroll
  for (int i = 0; i < 4; ++i) acc[i] = (f32x4)(0.0f);

  const ushort* srcb = src + (size_t)b * 257 * KP;
  int row = tid >> 1, half = tid & 1;
  const ushort* gsrc = srcb + (size_t)row * KP + half * 16;
  ushort* lds_dst = plane + row * PL + half * 16;

  for (int cic = 0; cic < NCHUNK; ++cic) {
    __syncthreads();
    {  // stage 256 rows x 32 ci (bf16) = 16 KB
      const float4* g = (const float4*)(gsrc + cic * 32);
      float4 v0 = g[0];
      float4 v1 = g[1];
      ((float4*)lds_dst)[0] = v0;
      ((float4*)lds_dst)[1] = v1;
    }
    __syncthreads();
    const ushort* wbase = wT + (size_t)co * KP + cic * 32 + quad * 8;
#pragma unroll
    for (int dx = 0; dx < 3; ++dx) {
      int sx = m + dx - 1;
      bool vx = (unsigned)sx < 16u;
      bf16x8 af[6];  // image rows y0-1 .. y0+4, shifted by dx
#pragma unroll
      for (int j = 0; j < 6; ++j) {
        int syr = y0 - 1 + j;
        bool v = vx && ((unsigned)syr < 16u);
        int ldsrow = v ? (syr * 16 + sx) : 256;
        af[j] = *(const bf16x8*)(plane + ldsrow * PL + quad * 8);
      }
#pragma unroll
      for (int dy = 0; dy < 3; ++dy) {
        int tap = dy * 3 + dx;
        bf16x8 bf = *(const bf16x8*)(wbase + (size_t)tap * 320 * KP);
#pragma unroll
        for (int mt = 0; mt < 4; ++mt) {
          acc[mt] = __builtin_amdgcn_mfma_f32_16x16x32_bf16(af[mt + dy], bf,
                                                            acc[mt], 0, 0, 0);
        }
      }
    }
  }

  float bv = bias[co];
  if (PLANAR_OUT) {
    float* dst = (float*)dstv;  // [BB][320][256]
#pragma unroll
    for (int mt = 0; mt < 4; ++mt) {
      f32x4 v = acc[mt] + bv;
      *(f32x4*)(dst + ((size_t)b * CC + co) * NPIX + (y0 + mt) * 16 + quad * 4) = v;
    }
  } else {
    ushort* dst = (ushort*)dstv;  // [BB][257][320]
#pragma unroll
    for (int mt = 0; mt < 4; ++mt) {
#pragma unroll
      for (int r = 0; r < 4; ++r) {
        float v = acc[mt][r] + bv;
        if (SILU) v = v / (1.0f + __expf(-v));
        int p = (y0 + mt) * 16 + quad * 4 + r;
        dst[((size_t)b * 257 + p) * 320 + co] = f2bf(v);
      }
    }
  }
}

// ---------------------------------------------------------------------------
// out = global_x + masked gather of planar cx2.
__global__ __launch_bounds__(256) void scatter_add(
    const float* __restrict__ gx, const float* __restrict__ cx2,
    const int* __restrict__ sy, const int* __restrict__ sx,
    float* __restrict__ out) {
  int blk = blockIdx.x;
  int part = blk & 3;
  int bc = blk >> 2;  // b*320 + c
  int b = bc / CC;
  int t = threadIdx.x;
  int e = part * 1024 + t * 4;
  int y = e >> 6, x0 = e & 63;
  size_t idx = (size_t)bc * 4096 + e;
  float4 g = *(const float4*)(gx + idx);
  int vy = sy[b * 64 + y];
  if (vy >= 0) {
    const float* cxp = cx2 + (size_t)bc * NPIX + vy * 16;
    int v0 = sx[b * 64 + x0 + 0]; if (v0 >= 0) g.x += cxp[v0];
    int v1 = sx[b * 64 + x0 + 1]; if (v1 >= 0) g.y += cxp[v1];
    int v2 = sx[b * 64 + x0 + 2]; if (v2 >= 0) g.z += cxp[v2];
    int v3 = sx[b * 64 + x0 + 3]; if (v3 >= 0) g.w += cxp[v3];
  }
  *(float4*)(out + idx) = g;
}

// ---------------------------------------------------------------------------
extern "C" void kernel_launch(void* const* d_in, const int* in_sizes, int n_in,
                              void* d_out, int out_size, void* d_ws, size_t ws_size,
                              hipStream_t stream) {
  const float* gx    = (const float*)d_in[0];
  const float* ctx   = (const float*)d_in[1];
  const float* ind   = (const float*)d_in[2];
  const float* bbox  = (const float*)d_in[3];
  const float* w_in  = (const float*)d_in[4];
  const float* b_in  = (const float*)d_in[5];
  const float* w_out = (const float*)d_in[6];
  const float* b_out = (const float*)d_in[7];
  float* out = (float*)d_out;

  char* ws = (char*)d_ws;
  float* cx2   = (float*)ws;  ws += (size_t)BB * CC * NPIX * 4;    // 10,485,760 B
  ushort* ctxP = (ushort*)ws; ws += (size_t)BB * 257 * 1056 * 2;   // 17,369,088 B
  ushort* wT1  = (ushort*)ws; ws += (size_t)9 * 320 * 1056 * 2;    //  6,082,560 B
  ushort* wT2  = (ushort*)ws; ws += (size_t)9 * 320 * 320 * 2;     //  1,843,200 B
  ushort* cx1P = (ushort*)ws; ws += (size_t)BB * 257 * 320 * 2;    //  5,263,360 B
  int* sy = (int*)ws;         ws += BB * 64 * 4;
  int* sx = (int*)ws;

  cast_ctx<<<dim3(BB, 257), 256, 0, stream>>>(ctx, ind, ctxP, cx1P);
  wt_tr<1026, 1056><<<11880, 256, 0, stream>>>(w_in, wT1);
  wt_tr<320, 320><<<3600, 256, 0, stream>>>(w_out, wT2);
  prep_maps<<<BB, 64, 0, stream>>>(bbox, sy, sx);
  conv_mfma<1056, 33, 1, 0><<<dim3(BB, 10), 512, 0, stream>>>(ctxP, wT1, b_in, (void*)cx1P);
  conv_mfma<320, 10, 0, 1><<<dim3(BB, 10), 512, 0, stream>>>(cx1P, wT2, b_out, (void*)cx2);
  scatter_add<<<BB * CC * 4, 256, 0, stream>>>(gx, cx2, sy, sx, out);
}